// Round 1
// baseline (627.985 us; speedup 1.0000x reference)
//
#include <hip/hip_runtime.h>

#define D 64          // D_IN == D_OUT
#define D_EDGE 16
#define NEG 0.01f

__device__ __forceinline__ float leaky(float v) { return v > 0.f ? v : NEG * v; }

// Kernel 1: per-node precompute.
//   x_t[n] = x[n] @ W2.T          (W2 [64][64])
//   A[n]   = x[n] @ W1[:, :64].T  (W1 [64][80], cols 0..63)
//   r[n]   = sum_j leaky(x[n][j]) * attn[64+j]
// thread-per-node; weights staged in LDS, read as wave-uniform broadcasts.
__global__ __launch_bounds__(256) void node_kernel(
    const float* __restrict__ x, const float* __restrict__ W1,
    const float* __restrict__ W2, const float* __restrict__ attn,
    float* __restrict__ A, float* __restrict__ xt, float* __restrict__ r, int N_)
{
    __shared__ float w2s[64 * 64];
    __shared__ float w1s[64 * 64];
    __shared__ float ah[64];
    for (int i = threadIdx.x; i < 64 * 64; i += 256) {
        w2s[i] = W2[i];
        int k = i >> 6, j = i & 63;
        w1s[i] = W1[k * 80 + j];
    }
    if (threadIdx.x < 64) ah[threadIdx.x] = attn[64 + threadIdx.x];
    __syncthreads();

    int n = blockIdx.x * 256 + threadIdx.x;
    if (n >= N_) return;

    const float4* x4 = (const float4*)(x + (size_t)n * D);
    float4 xr[16];
#pragma unroll
    for (int i = 0; i < 16; i++) xr[i] = x4[i];

    const float4* w2s4 = (const float4*)w2s;
    const float4* w1s4 = (const float4*)w1s;
    for (int k = 0; k < 64; k++) {
        float a = 0.f, b = 0.f;
#pragma unroll
        for (int j = 0; j < 16; j++) {
            float4 w = w2s4[k * 16 + j];
            a += xr[j].x * w.x + xr[j].y * w.y + xr[j].z * w.z + xr[j].w * w.w;
            float4 u = w1s4[k * 16 + j];
            b += xr[j].x * u.x + xr[j].y * u.y + xr[j].z * u.z + xr[j].w * u.w;
        }
        xt[(size_t)n * D + k] = a;
        A[(size_t)n * D + k]  = b;
    }

    float rr = 0.f;
#pragma unroll
    for (int j = 0; j < 16; j++) {
        rr += leaky(xr[j].x) * ah[4 * j + 0];
        rr += leaky(xr[j].y) * ah[4 * j + 1];
        rr += leaky(xr[j].z) * ah[4 * j + 2];
        rr += leaky(xr[j].w) * ah[4 * j + 3];
    }
    r[n] = rr;
}

// Kernel 2: one wave (64 lanes) per edge, grid-stride.
//   f_k   = A[src][k] + dot(edge_attr[e], W1[k, 64:80])   (lane k)
//   logit = sum_k leaky(f_k)*attn[k] + r[dst]
//   p     = exp(logit)   (no max-subtraction needed; logits are O(6))
//   denom[dst] += p;  out[dst][k] += p * x_t[src][k]
__global__ __launch_bounds__(256) void edge_kernel(
    const float* __restrict__ edge_attr, const int* __restrict__ src,
    const int* __restrict__ dst, const float* __restrict__ W1,
    const float* __restrict__ attn,
    const float* __restrict__ A, const float* __restrict__ xt,
    const float* __restrict__ r,
    float* __restrict__ out, float* __restrict__ denom, int E_)
{
    const int lane   = threadIdx.x & 63;
    const int wave   = blockIdx.x * (blockDim.x >> 6) + (threadIdx.x >> 6);
    const int nwaves = gridDim.x * (blockDim.x >> 6);

    // per-lane weight row W1[lane, 64:80] — 16 floats in registers, amortized
    const float4* wrow = (const float4*)(W1 + lane * 80 + 64);
    float4 w0 = wrow[0], w1 = wrow[1], w2 = wrow[2], w3 = wrow[3];
    float ak = attn[lane];

    const float4* ea4 = (const float4*)edge_attr;

    for (int e = wave; e < E_; e += nwaves) {
        int s = src[e];
        int d = dst[e];
        float4 e0 = ea4[e * 4 + 0], e1 = ea4[e * 4 + 1];
        float4 e2 = ea4[e * 4 + 2], e3 = ea4[e * 4 + 3];

        float f = A[(size_t)s * D + lane];
        f += e0.x * w0.x + e0.y * w0.y + e0.z * w0.z + e0.w * w0.w;
        f += e1.x * w1.x + e1.y * w1.y + e1.z * w1.z + e1.w * w1.w;
        f += e2.x * w2.x + e2.y * w2.y + e2.z * w2.z + e2.w * w2.w;
        f += e3.x * w3.x + e3.y * w3.y + e3.z * w3.z + e3.w * w3.w;

        float v = leaky(f) * ak;
        // 64-lane butterfly reduce — every lane ends with the full sum
#pragma unroll
        for (int off = 32; off > 0; off >>= 1) v += __shfl_xor(v, off, 64);

        float p = expf(v + r[d]);
        float m = xt[(size_t)s * D + lane];
        if (lane == 0) atomicAdd(denom + d, p);
        atomicAdd(out + (size_t)d * D + lane, p * m);
    }
}

// Kernel 3: out[n][k] = out[n][k] / denom[n] + bias[k]   (guard empty segments)
__global__ __launch_bounds__(256) void fin_kernel(
    float* __restrict__ out, const float* __restrict__ denom,
    const float* __restrict__ bias, int total)
{
    int i = blockIdx.x * 256 + threadIdx.x;
    if (i >= total) return;
    int n = i >> 6, k = i & 63;
    float dn = denom[n];
    float sc = dn > 0.f ? 1.f / dn : 0.f;
    out[i] = out[i] * sc + bias[k];
}

extern "C" void kernel_launch(void* const* d_in, const int* in_sizes, int n_in,
                              void* d_out, int out_size, void* d_ws, size_t ws_size,
                              hipStream_t stream)
{
    const float* x         = (const float*)d_in[0];
    const float* edge_attr = (const float*)d_in[1];
    const int*   src       = (const int*)d_in[2];
    const int*   dst       = (const int*)d_in[3];
    const float* W1        = (const float*)d_in[4];
    const float* W2        = (const float*)d_in[5];
    const float* attn      = (const float*)d_in[6];
    const float* bias      = (const float*)d_in[7];
    float* out = (float*)d_out;

    const int N_ = in_sizes[0] / D;   // 100000
    const int E_ = in_sizes[2];       // 1280000

    // workspace layout (fp32): A[N*64] | xt[N*64] | r[N] | denom[N]  (~52 MB)
    float* A     = (float*)d_ws;
    float* xt    = A  + (size_t)N_ * D;
    float* r     = xt + (size_t)N_ * D;
    float* denom = r  + N_;

    hipMemsetAsync(out,   0, (size_t)out_size * sizeof(float), stream);
    hipMemsetAsync(denom, 0, (size_t)N_ * sizeof(float), stream);

    node_kernel<<<(N_ + 255) / 256, 256, 0, stream>>>(x, W1, W2, attn, A, xt, r, N_);
    edge_kernel<<<8192, 256, 0, stream>>>(edge_attr, src, dst, W1, attn,
                                          A, xt, r, out, denom, E_);
    fin_kernel<<<((size_t)N_ * D + 255) / 256, 256, 0, stream>>>(out, denom, bias, N_ * D);
}